// Round 4
// baseline (1476.741 us; speedup 1.0000x reference)
//
#include <hip/hip_runtime.h>
#include <hip/hip_bf16.h>

#define N_NODES 100000
#define N_PAD 100032          // 1563 * 64
#define MM_BLOCKS 1563        // N_PAD / 64
#define RED_BLOCKS 64
#define N_EDGES 3200000
#define N_GRAPHS 1024
#define DIM 128
#define BN_EPS 1e-5f
#define SCAN_CHUNK 391        // 256 * 391 = 100096 >= N_NODES

// CSR build: LDS-histogram counting sort (no global atomics)
#define NCHUNK 32             // edge chunks; 32 * 100000 = N_EDGES exactly
#define CHUNK_E 100000
#define R_NODES 16384         // 16384 * 4B = 64 KB LDS histogram
#define NRANGES 7             // 7 * 16384 = 114688 >= N_NODES

typedef __attribute__((ext_vector_type(8))) short short8;
typedef __attribute__((ext_vector_type(4))) float floatx4;

__device__ __forceinline__ float bits2f(unsigned short u) {
    return __uint_as_float(((unsigned int)u) << 16);
}
__device__ __forceinline__ unsigned short f2b_rne(float f) {
    unsigned int u = __float_as_uint(f);
    unsigned int r = u + 0x7FFFu + ((u >> 16) & 1u);
    return (unsigned short)(r >> 16);
}
__device__ __forceinline__ float lo2f(unsigned int u) { return __uint_as_float(u << 16); }
__device__ __forceinline__ float hi2f(unsigned int u) { return __uint_as_float(u & 0xFFFF0000u); }

// ---------------- x (fp32) -> bf16 Hb0, vectorized ----------------
__global__ __launch_bounds__(256) void k_cvt0(const float4* __restrict__ x4,
                                              ushort4* __restrict__ o4) {
    size_t i = (size_t)blockIdx.x * 256 + threadIdx.x;   // exactly 3,200,000
    float4 v = x4[i];
    ushort4 o;
    o.x = f2b_rne(v.x); o.y = f2b_rne(v.y); o.z = f2b_rne(v.z); o.w = f2b_rne(v.w);
    o4[i] = o;
}

// ---------------- graph boundaries (batch sorted) ----------------

__global__ __launch_bounds__(256) void k_binit(int* __restrict__ startv, int* __restrict__ endv) {
    int i = blockIdx.x * 256 + threadIdx.x;
    if (i < N_GRAPHS) { startv[i] = 0; endv[i] = 0; }
}

__global__ __launch_bounds__(256) void k_bounds(const int* __restrict__ batch,
                                                int* __restrict__ startv, int* __restrict__ endv) {
    int i = blockIdx.x * 256 + threadIdx.x;
    if (i >= N_NODES) return;
    int g = batch[i];
    if (i == 0 || batch[i - 1] != g) startv[g] = i;
    if (i == N_NODES - 1 || batch[i + 1] != g) endv[g] = i + 1;
}

// ---------------- CSR build (atomic-free at global scope) ----------------
// dst space split into 7 ranges of 16384 (64KB LDS hist), edges into 32
// chunks of 100000. Block (chunk, range) streams its chunk's dsts (int4) and
// ranks in-range edges via LDS atomicAdd (CU-local, no fabric traffic).
__global__ __launch_bounds__(256) void k_deg2(const int* __restrict__ ei,
                                              int* __restrict__ degC,   // [NCHUNK][N_NODES]
                                              int* __restrict__ rank) {
    __shared__ int hist[R_NODES];
    int chunk = blockIdx.x / NRANGES;
    int range = blockIdx.x - chunk * NRANGES;
    int base = range * R_NODES;
    for (int i = threadIdx.x; i < R_NODES; i += 256) hist[i] = 0;
    __syncthreads();

    const int4* d4 = (const int4*)(ei + N_EDGES + chunk * CHUNK_E);
    int* rk = rank + chunk * CHUNK_E;
    const int niter = CHUNK_E / 4;   // 25000
    for (int i = threadIdx.x; i < niter; i += 256) {
        int4 d = d4[i];
        unsigned int r0 = (unsigned int)(d.x - base);
        unsigned int r1 = (unsigned int)(d.y - base);
        unsigned int r2 = (unsigned int)(d.z - base);
        unsigned int r3 = (unsigned int)(d.w - base);
        if (r0 < R_NODES) rk[4 * i]     = atomicAdd(&hist[r0], 1);
        if (r1 < R_NODES) rk[4 * i + 1] = atomicAdd(&hist[r1], 1);
        if (r2 < R_NODES) rk[4 * i + 2] = atomicAdd(&hist[r2], 1);
        if (r3 < R_NODES) rk[4 * i + 3] = atomicAdd(&hist[r3], 1);
    }
    __syncthreads();

    int top = N_NODES - base; if (top > R_NODES) top = R_NODES;
    int* dC = degC + (size_t)chunk * N_NODES + base;
    for (int i = threadIdx.x; i < top; i += 256) dC[i] = hist[i];
}

// per-node exclusive prefix over the NCHUNK copies, in place; total degree out
__global__ __launch_bounds__(256) void k_comb(int* __restrict__ degC,
                                              int* __restrict__ deg) {
    int i = blockIdx.x * 256 + threadIdx.x;
    if (i >= N_NODES) return;
    int run = 0;
#pragma unroll
    for (int c = 0; c < NCHUNK; ++c) {
        int* p = degC + (size_t)c * N_NODES + i;
        int t = *p;
        *p = run;
        run += t;
    }
    deg[i] = run;
}

// hierarchical scan: A) per-block sums  B) scan of 256 block sums  C) per-node offsets
__global__ __launch_bounds__(256) void k_scanA(const int* __restrict__ deg, int* __restrict__ bsum) {
    __shared__ int red[256];
    int b = blockIdx.x, t = threadIdx.x;
    int base = b * SCAN_CHUNK;
    int end = base + SCAN_CHUNK; if (end > N_NODES) end = N_NODES;
    int s = 0;
    for (int i = base + t; i < end; i += 256) s += deg[i];
    red[t] = s; __syncthreads();
    for (int st = 128; st > 0; st >>= 1) { if (t < st) red[t] += red[t + st]; __syncthreads(); }
    if (t == 0) bsum[b] = red[0];
}

__global__ __launch_bounds__(256) void k_scanB(const int* __restrict__ bsum,
                                               int* __restrict__ bbase, int* __restrict__ offend) {
    __shared__ int v[256];
    int t = threadIdx.x;
    int mine = bsum[t];
    v[t] = mine; __syncthreads();
    for (int d = 1; d < 256; d <<= 1) {
        int x = (t >= d) ? v[t - d] : 0; __syncthreads();
        v[t] += x; __syncthreads();
    }
    bbase[t] = v[t] - mine;
    if (t == 255) *offend = v[255];
}

__global__ __launch_bounds__(256) void k_scanC(const int* __restrict__ deg,
                                               const int* __restrict__ bbase,
                                               int* __restrict__ off) {
    __shared__ int red[256];
    int b = blockIdx.x, t = threadIdx.x;
    int base = b * SCAN_CHUNK;
    int end = base + SCAN_CHUNK; if (end > N_NODES) end = N_NODES;
    int n0 = base + 2 * t, n1 = n0 + 1;
    int d0 = (n0 < end) ? deg[n0] : 0;
    int d1 = (n1 < end) ? deg[n1] : 0;
    int mine = d0 + d1;
    red[t] = mine; __syncthreads();
    for (int d = 1; d < 256; d <<= 1) {
        int x = (t >= d) ? red[t - d] : 0; __syncthreads();
        red[t] += x; __syncthreads();
    }
    int excl = red[t] - mine + bbase[b];
    if (n0 < end) off[n0] = excl;
    if (n1 < end) off[n1] = excl + d0;
}

// atomic-free fill: position = off[dst] + chunk-base + rank
__global__ __launch_bounds__(256) void k_fill(const int* __restrict__ ei,
                                              const int* __restrict__ off,
                                              const int* __restrict__ degC,
                                              const int* __restrict__ rank,
                                              int* __restrict__ csr_src) {
    int e = blockIdx.x * 256 + threadIdx.x;
    if (e < N_EDGES) {
        int chunk = e / CHUNK_E;     // constant division -> magic mul
        int dst = ei[N_EDGES + e];
        csr_src[off[dst] + degC[(size_t)chunk * N_NODES + dst] + rank[e]] = ei[e];
    }
}

// ------- weight transpose + fp32->bf16: Wt[mat][n*128+k] = bf16(W[mat][k*128+n])
__global__ __launch_bounds__(256) void k_tw(const float* __restrict__ w1,
                                            const float* __restrict__ w2,
                                            const float* __restrict__ lw1,
                                            const float* __restrict__ lw2,
                                            unsigned short* __restrict__ Wt) {
    int bid = blockIdx.x;                     // 512 blocks
    int mat = bid >> 6;
    int t = (bid & 63) * 256 + threadIdx.x;   // 0..16383
    int k = t >> 7, n = t & 127;
    const float* src;
    if (mat == 0) src = w1;
    else if (mat == 1) src = w2;
    else if (mat < 5) src = lw1 + (size_t)(mat - 2) * 16384;
    else src = lw2 + (size_t)(mat - 5) * 16384;
    Wt[(size_t)mat * 16384 + n * 128 + k] = f2b_rne(src[t]);
}

// ---------------- aggregation: A[dst] = H[dst] + sum_{src in N(dst)} H[src] --
// one wave per dst; 16 lanes x 16B per row => 4 rows/load-instr; main loop 8
// rows in flight; tail is ONE masked batch of 32. R2 lesson: never fuse MFMA
// behind this gather. R3 counters: latency-bound (BW tracked occupancy 1:1 in
// the R2 accident), so this round raises occupancy: 1024-thread blocks (16
// waves, one dst per wave, grid 6250) amortize block dispatch/drain churn;
// __launch_bounds__(1024,8) keeps VGPR <= 64 so 2 blocks/CU co-reside (100%).
__global__ __launch_bounds__(1024, 8) void k_agg(const uint4* __restrict__ H4,
                                                 const int* __restrict__ off,
                                                 const int* __restrict__ csr_src,
                                                 uint4* __restrict__ A4) {
    int wave = threadIdx.x >> 6;     // 0..15
    int lane = threadIdx.x & 63;
    int g4 = lane >> 4;        // neighbor sub-slot 0..3
    int c = lane & 15;         // uint4 index within 256B row
    int dst = blockIdx.x * 16 + wave;
    if (dst >= N_NODES) return;
    int s = off[dst], e = off[dst + 1];

    float acc[8];
    {
        uint4 h = H4[(size_t)dst * 16 + c];
        if (g4 == 0) {
            acc[0] = lo2f(h.x); acc[1] = hi2f(h.x);
            acc[2] = lo2f(h.y); acc[3] = hi2f(h.y);
            acc[4] = lo2f(h.z); acc[5] = hi2f(h.z);
            acc[6] = lo2f(h.w); acc[7] = hi2f(h.w);
        } else {
#pragma unroll
            for (int j = 0; j < 8; ++j) acc[j] = 0.f;
        }
    }

#define ADD8(v) do { \
        acc[0] += lo2f((v).x); acc[1] += hi2f((v).x); \
        acc[2] += lo2f((v).y); acc[3] += hi2f((v).y); \
        acc[4] += lo2f((v).z); acc[5] += hi2f((v).z); \
        acc[6] += lo2f((v).w); acc[7] += hi2f((v).w); } while (0)

    int i = s;
    for (; i + 32 <= e; i += 32) {
        int i0 = i + g4;
        int s0 = csr_src[i0];
        int s1 = csr_src[i0 + 4];
        int s2 = csr_src[i0 + 8];
        int s3 = csr_src[i0 + 12];
        int s4 = csr_src[i0 + 16];
        int s5 = csr_src[i0 + 20];
        int s6 = csr_src[i0 + 24];
        int s7 = csr_src[i0 + 28];
        uint4 v0 = H4[(size_t)s0 * 16 + c];
        uint4 v1 = H4[(size_t)s1 * 16 + c];
        uint4 v2 = H4[(size_t)s2 * 16 + c];
        uint4 v3 = H4[(size_t)s3 * 16 + c];
        uint4 v4 = H4[(size_t)s4 * 16 + c];
        uint4 v5 = H4[(size_t)s5 * 16 + c];
        uint4 v6 = H4[(size_t)s6 * 16 + c];
        uint4 v7 = H4[(size_t)s7 * 16 + c];
        ADD8(v0); ADD8(v1); ADD8(v2); ADD8(v3);
        ADD8(v4); ADD8(v5); ADD8(v6); ADD8(v7);
    }
    if (i < e) {               // single masked batch, full 8-deep MLP
        int last = e - 1;
        int i0 = i + g4;
        int x0 = i0,      x1 = i0 + 4,  x2 = i0 + 8,  x3 = i0 + 12;
        int x4i = i0 + 16, x5 = i0 + 20, x6 = i0 + 24, x7 = i0 + 28;
        int s0 = csr_src[x0 < e ? x0 : last];
        int s1 = csr_src[x1 < e ? x1 : last];
        int s2 = csr_src[x2 < e ? x2 : last];
        int s3 = csr_src[x3 < e ? x3 : last];
        int s4 = csr_src[x4i < e ? x4i : last];
        int s5 = csr_src[x5 < e ? x5 : last];
        int s6 = csr_src[x6 < e ? x6 : last];
        int s7 = csr_src[x7 < e ? x7 : last];
        uint4 v0 = H4[(size_t)s0 * 16 + c];
        uint4 v1 = H4[(size_t)s1 * 16 + c];
        uint4 v2 = H4[(size_t)s2 * 16 + c];
        uint4 v3 = H4[(size_t)s3 * 16 + c];
        uint4 v4 = H4[(size_t)s4 * 16 + c];
        uint4 v5 = H4[(size_t)s5 * 16 + c];
        uint4 v6 = H4[(size_t)s6 * 16 + c];
        uint4 v7 = H4[(size_t)s7 * 16 + c];
        if (x0 < e) ADD8(v0);
        if (x1 < e) ADD8(v1);
        if (x2 < e) ADD8(v2);
        if (x3 < e) ADD8(v3);
        if (x4i < e) ADD8(v4);
        if (x5 < e) ADD8(v5);
        if (x6 < e) ADD8(v6);
        if (x7 < e) ADD8(v7);
    }
#undef ADD8

#pragma unroll
    for (int j = 0; j < 8; ++j) {
        acc[j] += __shfl_xor(acc[j], 16, 64);
        acc[j] += __shfl_xor(acc[j], 32, 64);
    }
    if (g4 == 0) {
        uint4 o;
        o.x = (unsigned int)f2b_rne(acc[0]) | ((unsigned int)f2b_rne(acc[1]) << 16);
        o.y = (unsigned int)f2b_rne(acc[2]) | ((unsigned int)f2b_rne(acc[3]) << 16);
        o.z = (unsigned int)f2b_rne(acc[4]) | ((unsigned int)f2b_rne(acc[5]) << 16);
        o.w = (unsigned int)f2b_rne(acc[6]) | ((unsigned int)f2b_rne(acc[7]) << 16);
        A4[(size_t)dst * 16 + c] = o;
    }
}

// ------- MFMA GEMM 1: Yb = bf16(A @ W1 + b1), fused BN column stats ---------
__global__ __launch_bounds__(256) void k_mm1(const unsigned short* __restrict__ A,
                                             const unsigned short* __restrict__ Wt,
                                             const float* __restrict__ bias,
                                             unsigned short* __restrict__ Yb,
                                             float* __restrict__ partials) {
    __shared__ float sWS[4 * 128];
    __shared__ float s2WS[4 * 128];
    int wave = threadIdx.x >> 6, lane = threadIdx.x & 63;
    int quad = lane >> 4, l16 = lane & 15;
    int mload = blockIdx.x * 64 + wave * 16 + l16;      // < N_PAD

    short8 a[4];
    const unsigned short* arow = A + (size_t)mload * 128 + quad * 8;
#pragma unroll
    for (int kc = 0; kc < 4; ++kc) a[kc] = *(const short8*)(arow + kc * 32);

    floatx4 acc[8];
#pragma unroll
    for (int nt = 0; nt < 8; ++nt) {
        floatx4 z = {0.f, 0.f, 0.f, 0.f};
        acc[nt] = z;
        const unsigned short* wrow = Wt + (size_t)(nt * 16 + l16) * 128 + quad * 8;
#pragma unroll
        for (int kc = 0; kc < 4; ++kc) {
            short8 b = *(const short8*)(wrow + kc * 32);
            acc[nt] = __builtin_amdgcn_mfma_f32_16x16x32_bf16(a[kc], b, acc[nt], 0, 0, 0);
        }
    }

    int mrow0 = blockIdx.x * 64 + wave * 16 + quad * 4;
    float s_nt[8], s2_nt[8];
#pragma unroll
    for (int nt = 0; nt < 8; ++nt) {
        int n = nt * 16 + l16;
        float bn = bias[n];
        float s = 0.f, s2 = 0.f;
#pragma unroll
        for (int r = 0; r < 4; ++r) {
            int mm = mrow0 + r;
            if (mm < N_NODES) {
                float val = acc[nt][r] + bn;
                Yb[(size_t)mm * 128 + n] = f2b_rne(val);
                s += val;
                s2 = fmaf(val, val, s2);
            }
        }
        s_nt[nt] = s; s2_nt[nt] = s2;
    }
#pragma unroll
    for (int nt = 0; nt < 8; ++nt) {
        s_nt[nt] += __shfl_xor(s_nt[nt], 16, 64);
        s_nt[nt] += __shfl_xor(s_nt[nt], 32, 64);
        s2_nt[nt] += __shfl_xor(s2_nt[nt], 16, 64);
        s2_nt[nt] += __shfl_xor(s2_nt[nt], 32, 64);
    }
    if (quad == 0) {
#pragma unroll
        for (int nt = 0; nt < 8; ++nt) {
            sWS[wave * 128 + nt * 16 + l16] = s_nt[nt];
            s2WS[wave * 128 + nt * 16 + l16] = s2_nt[nt];
        }
    }
    __syncthreads();
    int tid = threadIdx.x;
    if (tid < 128) {
        float v = sWS[tid] + sWS[128 + tid] + sWS[256 + tid] + sWS[384 + tid];
        partials[(size_t)blockIdx.x * 256 + tid] = v;
    } else {
        int cc = tid - 128;
        float v = s2WS[cc] + s2WS[128 + cc] + s2WS[256 + cc] + s2WS[384 + cc];
        partials[(size_t)blockIdx.x * 256 + 128 + cc] = v;
    }
}

// ---- hierarchical partial reduce: 1563 rows -> RED_BLOCKS rows (coalesced) --
__global__ __launch_bounds__(256) void k_redp(const float* __restrict__ partials,
                                              float* __restrict__ pred) {
    int b = blockIdx.x;        // 0..RED_BLOCKS-1
    int tid = threadIdx.x;
    float s = 0.f;
    for (int r = b; r < MM_BLOCKS; r += RED_BLOCKS) s += partials[(size_t)r * 256 + tid];
    pred[(size_t)b * 256 + tid] = s;
}

__global__ __launch_bounds__(256) void k_finalize(const float* __restrict__ pred,
                                                  float* __restrict__ stats,
                                                  const float* __restrict__ g,
                                                  const float* __restrict__ be) {
    __shared__ float red[256];
    int tid = threadIdx.x;
    float s = 0.f;
#pragma unroll 8
    for (int b = 0; b < RED_BLOCKS; ++b) s += pred[(size_t)b * 256 + tid];
    red[tid] = s;
    __syncthreads();
    if (tid < 128) {
        float sum = red[tid], sumsq = red[128 + tid];
        const float invN = 1.f / (float)N_NODES;
        float m = sum * invN;
        float v = sumsq * invN - m * m;
        float rstd = rsqrtf(v + BN_EPS);
        float sca = g[tid] * rstd;
        stats[tid] = sca;
        stats[128 + tid] = be[tid] - m * sca;
    }
}

// ---- MFMA GEMM 2: H = relu( relu(Yb*sc+sh) @ W2 + b2 ), bf16 in/out --------
__global__ __launch_bounds__(256) void k_mm2(const unsigned short* __restrict__ Yb,
                                             const unsigned short* __restrict__ Wt,
                                             const float* __restrict__ bias,
                                             const float* __restrict__ stats,
                                             unsigned short* __restrict__ Hb) {
    int wave = threadIdx.x >> 6, lane = threadIdx.x & 63;
    int quad = lane >> 4, l16 = lane & 15;
    int mload = blockIdx.x * 64 + wave * 16 + l16;

    const unsigned short* yrow = Yb + (size_t)mload * 128;
    short8 a[4];
#pragma unroll
    for (int kc = 0; kc < 4; ++kc) {
        int k0 = kc * 32 + quad * 8;
        union { short8 s8; unsigned short u[8]; } q, p;
        q.s8 = *(const short8*)(yrow + k0);
#pragma unroll
        for (int j = 0; j < 8; ++j) {
            float sc = stats[k0 + j];
            float sh = stats[128 + k0 + j];
            float t = fmaxf(fmaf(bits2f(q.u[j]), sc, sh), 0.f);
            p.u[j] = f2b_rne(t);
        }
        a[kc] = p.s8;
    }

    floatx4 acc[8];
#pragma unroll
    for (int nt = 0; nt < 8; ++nt) {
        floatx4 z = {0.f, 0.f, 0.f, 0.f};
        acc[nt] = z;
        const unsigned short* wrow = Wt + (size_t)(nt * 16 + l16) * 128 + quad * 8;
#pragma unroll
        for (int kc = 0; kc < 4; ++kc) {
            short8 b = *(const short8*)(wrow + kc * 32);
            acc[nt] = __builtin_amdgcn_mfma_f32_16x16x32_bf16(a[kc], b, acc[nt], 0, 0, 0);
        }
    }

    int mrow0 = blockIdx.x * 64 + wave * 16 + quad * 4;
#pragma unroll
    for (int nt = 0; nt < 8; ++nt) {
        int n = nt * 16 + l16;
        float bn = bias[n];
#pragma unroll
        for (int r = 0; r < 4; ++r) {
            int mm = mrow0 + r;
            if (mm < N_NODES) {
                float h = fmaxf(acc[nt][r] + bn, 0.f);
                Hb[(size_t)mm * 128 + n] = f2b_rne(h);
            }
        }
    }
}

// ------- global add pool (bf16 in, fp32 out), 2 row-halves x 128 cols -------
__global__ __launch_bounds__(256) void k_pool(const unsigned short* __restrict__ Hb,
                                              const int* __restrict__ startv,
                                              const int* __restrict__ endv,
                                              float* __restrict__ gr, int loff) {
    __shared__ float part[128];
    int g = blockIdx.x;
    int tid = threadIdx.x;
    int c = tid & 127, half = tid >> 7;      // half 0: even rows, half 1: odd rows
    int s = startv[g], e = endv[g];
    float acc = 0.f;
    int r = s + half;
    for (; r + 7 <= e; r += 8) {             // rows r, r+2, r+4, r+6 all < e
        unsigned short a0 = Hb[(size_t)r * 128 + c];
        unsigned short a1 = Hb[(size_t)(r + 2) * 128 + c];
        unsigned short a2 = Hb[(size_t)(r + 4) * 128 + c];
        unsigned short a3 = Hb[(size_t)(r + 6) * 128 + c];
        acc += bits2f(a0) + bits2f(a1) + bits2f(a2) + bits2f(a3);
    }
    for (; r < e; r += 2) acc += bits2f(Hb[(size_t)r * 128 + c]);
    if (half) part[c] = acc;
    __syncthreads();
    if (!half) gr[(size_t)g * (4 * DIM) + loff + c] = acc + part[c];
}

// ---------------- classifier (fp32 weights, fp32 out) ----------------

__global__ __launch_bounds__(128) void k_cls1(const float* __restrict__ gr,
                                              const float* __restrict__ w,
                                              const float* __restrict__ b,
                                              float* __restrict__ out) {
    __shared__ float row[512];
    int g = blockIdx.x, tid = threadIdx.x;
    for (int i = tid; i < 512; i += 128) row[i] = gr[(size_t)g * 512 + i];
    __syncthreads();
    float acc = b[tid];
    for (int k = 0; k < 512; ++k) acc = fmaf(row[k], w[k * 128 + tid], acc);
    out[(size_t)g * 128 + tid] = fmaxf(acc, 0.f);
}

__global__ __launch_bounds__(64) void k_cls2(const float* __restrict__ gr1,
                                             const float* __restrict__ w,
                                             const float* __restrict__ b,
                                             float* __restrict__ out) {
    __shared__ float row[128];
    int g = blockIdx.x, tid = threadIdx.x;
    row[tid] = gr1[(size_t)g * 128 + tid];
    row[tid + 64] = gr1[(size_t)g * 128 + tid + 64];
    __syncthreads();
    float acc = b[tid];
    for (int k = 0; k < 128; ++k) acc = fmaf(row[k], w[k * 64 + tid], acc);
    out[(size_t)g * 64 + tid] = fmaxf(acc, 0.f);
}

__global__ __launch_bounds__(256) void k_cls3(const float* __restrict__ gr2,
                                              const float* __restrict__ w,
                                              const float* __restrict__ b,
                                              float* __restrict__ out) {
    int idx = blockIdx.x * 256 + threadIdx.x;
    if (idx < N_GRAPHS * 2) {
        int g = idx >> 1, j = idx & 1;
        float acc = b[j];
        const float* r = gr2 + (size_t)g * 64;
        for (int k = 0; k < 64; ++k) acc = fmaf(r[k], w[k * 2 + j], acc);
        out[idx] = acc;
    }
}

// ---------------- launch ----------------

extern "C" void kernel_launch(void* const* d_in, const int* in_sizes, int n_in,
                              void* d_out, int out_size, void* d_ws, size_t ws_size,
                              hipStream_t stream) {
    const float* x = (const float*)d_in[0];
    const int* ei = (const int*)d_in[1];
    const int* batch = (const int*)d_in[2];
    const float* b1 = (const float*)d_in[4];
    const float* g1 = (const float*)d_in[5];
    const float* be1 = (const float*)d_in[6];
    const float* b2 = (const float*)d_in[8];
    const float* lb1 = (const float*)d_in[10];
    const float* lg1 = (const float*)d_in[11];
    const float* lbe1 = (const float*)d_in[12];
    const float* lb2 = (const float*)d_in[14];
    const float* cw1 = (const float*)d_in[15];
    const float* cb1 = (const float*)d_in[16];
    const float* cw2 = (const float*)d_in[17];
    const float* cb2 = (const float*)d_in[18];
    const float* cw3 = (const float*)d_in[19];
    const float* cb3 = (const float*)d_in[20];

    // workspace layout (float units; every segment 16B-aligned)
    float* ws = (float*)d_ws;
    unsigned short* Yb = (unsigned short*)ws;                     // N_PAD*128 bf16
    float* gr = ws + (size_t)N_PAD * 64;                          // 1024*512
    float* gr1 = gr + (size_t)N_GRAPHS * 512;                     // 1024*128
    float* gr2 = gr1 + (size_t)N_GRAPHS * 128;                    // 1024*64
    float* stats = gr2 + (size_t)N_GRAPHS * 64;                   // 256
    float* partials = stats + 256;                                // 1563*256
    float* pred = partials + (size_t)MM_BLOCKS * 256;             // 64*256
    float* p_end = pred + (size_t)RED_BLOCKS * 256;
    int* startv = (int*)p_end;
    int* endv = startv + N_GRAPHS;
    unsigned short* Wt = (unsigned short*)(endv + N_GRAPHS);      // 8*16384 bf16
    unsigned short* A = Wt + (size_t)8 * 16384;                   // N_PAD*128 bf16
    unsigned short* Hb0 = A + (size_t)N_PAD * 128;                // bf16(x)
    unsigned short* Hb1 = Hb0 + (size_t)N_NODES * 128;            // layer H
    int* degC = (int*)(Hb1 + (size_t)N_NODES * 128);              // NCHUNK*N_NODES
    int* deg = degC + (size_t)NCHUNK * N_NODES;                   // N_NODES
    int* rank = deg + N_NODES;                                    // N_EDGES
    int* offarr = rank + N_EDGES;                                 // N_NODES+1
    int* csr_src = offarr + (N_NODES + 4);                        // N_EDGES
    int* bsum = csr_src + N_EDGES;                                // 256
    int* bbase = bsum + 256;                                      // 256

    k_cvt0<<<12500, 256, 0, stream>>>((const float4*)x, (ushort4*)Hb0);
    k_binit<<<4, 256, 0, stream>>>(startv, endv);
    k_bounds<<<(N_NODES + 255) / 256, 256, 0, stream>>>(batch, startv, endv);
    k_deg2<<<NCHUNK * NRANGES, 256, 0, stream>>>(ei, degC, rank);
    k_comb<<<(N_NODES + 255) / 256, 256, 0, stream>>>(degC, deg);
    k_scanA<<<256, 256, 0, stream>>>(deg, bsum);
    k_scanB<<<1, 256, 0, stream>>>(bsum, bbase, &offarr[N_NODES]);
    k_scanC<<<256, 256, 0, stream>>>(deg, bbase, offarr);
    k_fill<<<N_EDGES / 256, 256, 0, stream>>>(ei, offarr, degC, rank, csr_src);
    k_tw<<<512, 256, 0, stream>>>((const float*)d_in[3], (const float*)d_in[7],
                                  (const float*)d_in[9], (const float*)d_in[13], Wt);

    for (int l = 0; l < 4; ++l) {
        const unsigned short* aggIn = (l == 0) ? Hb0 : Hb1;

        const unsigned short* W1t = Wt + (size_t)((l == 0) ? 0 : (1 + l)) * 16384;
        const unsigned short* W2t = Wt + (size_t)((l == 0) ? 1 : (4 + l)) * 16384;
        const float* B1 = (l == 0) ? b1 : lb1 + (size_t)(l - 1) * 128;
        const float* B2 = (l == 0) ? b2 : lb2 + (size_t)(l - 1) * 128;
        const float* G = (l == 0) ? g1 : lg1 + (size_t)(l - 1) * 128;
        const float* BE = (l == 0) ? be1 : lbe1 + (size_t)(l - 1) * 128;

        k_agg<<<6250, 1024, 0, stream>>>((const uint4*)aggIn, offarr, csr_src,
                                         (uint4*)A);
        k_mm1<<<MM_BLOCKS, 256, 0, stream>>>(A, W1t, B1, Yb, partials);
        k_redp<<<RED_BLOCKS, 256, 0, stream>>>(partials, pred);
        k_finalize<<<1, 256, 0, stream>>>(pred, stats, G, BE);
        k_mm2<<<MM_BLOCKS, 256, 0, stream>>>(Yb, W2t, B2, stats, Hb1);
        k_pool<<<N_GRAPHS, 256, 0, stream>>>(Hb1, startv, endv, gr, l * DIM);
    }

    k_cls1<<<N_GRAPHS, 128, 0, stream>>>(gr, cw1, cb1, gr1);
    k_cls2<<<N_GRAPHS, 64, 0, stream>>>(gr1, cw2, cb2, gr2);
    k_cls3<<<8, 256, 0, stream>>>(gr2, cw3, cb3, (float*)d_out);
}

// Round 5
// 1210.981 us; speedup vs baseline: 1.2195x; 1.2195x over previous
//
#include <hip/hip_runtime.h>
#include <hip/hip_bf16.h>

#define N_NODES 100000
#define N_PAD 100032          // 1563 * 64
#define MM_BLOCKS 1563        // N_PAD / 64
#define RED_BLOCKS 64
#define N_EDGES 3200000
#define N_GRAPHS 1024
#define DIM 128
#define BN_EPS 1e-5f
#define SCAN_CHUNK 391        // 256 * 391 = 100096 >= N_NODES

// CSR build: LDS-histogram counting sort (no global atomics)
#define NCHUNK 32             // edge chunks; 32 * 100000 = N_EDGES exactly
#define CHUNK_E 100000
#define R_NODES 16384         // 16384 * 4B = 64 KB LDS histogram
#define NRANGES 7             // 7 * 16384 = 114688 >= N_NODES

typedef __attribute__((ext_vector_type(8))) short short8;
typedef __attribute__((ext_vector_type(4))) float floatx4;

__device__ __forceinline__ float bits2f(unsigned short u) {
    return __uint_as_float(((unsigned int)u) << 16);
}
__device__ __forceinline__ unsigned short f2b_rne(float f) {
    unsigned int u = __float_as_uint(f);
    unsigned int r = u + 0x7FFFu + ((u >> 16) & 1u);
    return (unsigned short)(r >> 16);
}
__device__ __forceinline__ float lo2f(unsigned int u) { return __uint_as_float(u << 16); }
__device__ __forceinline__ float hi2f(unsigned int u) { return __uint_as_float(u & 0xFFFF0000u); }

// ---------------- x (fp32) -> bf16 Hb0, vectorized ----------------
__global__ __launch_bounds__(256) void k_cvt0(const float4* __restrict__ x4,
                                              ushort4* __restrict__ o4) {
    size_t i = (size_t)blockIdx.x * 256 + threadIdx.x;   // exactly 3,200,000
    float4 v = x4[i];
    ushort4 o;
    o.x = f2b_rne(v.x); o.y = f2b_rne(v.y); o.z = f2b_rne(v.z); o.w = f2b_rne(v.w);
    o4[i] = o;
}

// ---------------- graph boundaries (batch sorted) ----------------

__global__ __launch_bounds__(256) void k_binit(int* __restrict__ startv, int* __restrict__ endv,
                                               int* __restrict__ ctr) {
    int i = blockIdx.x * 256 + threadIdx.x;
    if (i < N_GRAPHS) { startv[i] = 0; endv[i] = 0; }
    if (i == 0) *ctr = 0;
}

__global__ __launch_bounds__(256) void k_bounds(const int* __restrict__ batch,
                                                int* __restrict__ startv, int* __restrict__ endv) {
    int i = blockIdx.x * 256 + threadIdx.x;
    if (i >= N_NODES) return;
    int g = batch[i];
    if (i == 0 || batch[i - 1] != g) startv[g] = i;
    if (i == N_NODES - 1 || batch[i + 1] != g) endv[g] = i + 1;
}

// ---------------- CSR build (atomic-free at global scope) ----------------
// dst space split into 7 ranges of 16384 (64KB LDS hist), edges into 32
// chunks of 100000. Block (chunk, range) streams its chunk's dsts (int4) and
// ranks in-range edges via LDS atomicAdd (CU-local, no fabric traffic).
__global__ __launch_bounds__(256) void k_deg2(const int* __restrict__ ei,
                                              int* __restrict__ degC,   // [NCHUNK][N_NODES]
                                              int* __restrict__ rank) {
    __shared__ int hist[R_NODES];
    int chunk = blockIdx.x / NRANGES;
    int range = blockIdx.x - chunk * NRANGES;
    int base = range * R_NODES;
    for (int i = threadIdx.x; i < R_NODES; i += 256) hist[i] = 0;
    __syncthreads();

    const int4* d4 = (const int4*)(ei + N_EDGES + chunk * CHUNK_E);
    int* rk = rank + chunk * CHUNK_E;
    const int niter = CHUNK_E / 4;   // 25000
    for (int i = threadIdx.x; i < niter; i += 256) {
        int4 d = d4[i];
        unsigned int r0 = (unsigned int)(d.x - base);
        unsigned int r1 = (unsigned int)(d.y - base);
        unsigned int r2 = (unsigned int)(d.z - base);
        unsigned int r3 = (unsigned int)(d.w - base);
        if (r0 < R_NODES) rk[4 * i]     = atomicAdd(&hist[r0], 1);
        if (r1 < R_NODES) rk[4 * i + 1] = atomicAdd(&hist[r1], 1);
        if (r2 < R_NODES) rk[4 * i + 2] = atomicAdd(&hist[r2], 1);
        if (r3 < R_NODES) rk[4 * i + 3] = atomicAdd(&hist[r3], 1);
    }
    __syncthreads();

    int top = N_NODES - base; if (top > R_NODES) top = R_NODES;
    int* dC = degC + (size_t)chunk * N_NODES + base;
    for (int i = threadIdx.x; i < top; i += 256) dC[i] = hist[i];
}

// per-node exclusive prefix over the NCHUNK copies, in place; total degree out.
// R4 lesson class: 32 DEPENDENT strided loads/thread at ~1.5 blocks/CU is
// latency-exposed -> batch all 32 loads into regs (independent, pipelined),
// then prefix + store.
__global__ __launch_bounds__(256) void k_comb(int* __restrict__ degC,
                                              int* __restrict__ deg) {
    int i = blockIdx.x * 256 + threadIdx.x;
    if (i >= N_NODES) return;
    int v[NCHUNK];
#pragma unroll
    for (int c = 0; c < NCHUNK; ++c) v[c] = degC[(size_t)c * N_NODES + i];
    int run = 0;
#pragma unroll
    for (int c = 0; c < NCHUNK; ++c) {
        degC[(size_t)c * N_NODES + i] = run;
        run += v[c];
    }
    deg[i] = run;
}

// hierarchical scan: A) per-block sums  B) scan of 256 block sums  C) per-node offsets
__global__ __launch_bounds__(256) void k_scanA(const int* __restrict__ deg, int* __restrict__ bsum) {
    __shared__ int red[256];
    int b = blockIdx.x, t = threadIdx.x;
    int base = b * SCAN_CHUNK;
    int end = base + SCAN_CHUNK; if (end > N_NODES) end = N_NODES;
    int s = 0;
    for (int i = base + t; i < end; i += 256) s += deg[i];
    red[t] = s; __syncthreads();
    for (int st = 128; st > 0; st >>= 1) { if (t < st) red[t] += red[t + st]; __syncthreads(); }
    if (t == 0) bsum[b] = red[0];
}

__global__ __launch_bounds__(256) void k_scanB(const int* __restrict__ bsum,
                                               int* __restrict__ bbase, int* __restrict__ offend) {
    __shared__ int v[256];
    int t = threadIdx.x;
    int mine = bsum[t];
    v[t] = mine; __syncthreads();
    for (int d = 1; d < 256; d <<= 1) {
        int x = (t >= d) ? v[t - d] : 0; __syncthreads();
        v[t] += x; __syncthreads();
    }
    bbase[t] = v[t] - mine;
    if (t == 255) *offend = v[255];
}

__global__ __launch_bounds__(256) void k_scanC(const int* __restrict__ deg,
                                               const int* __restrict__ bbase,
                                               int* __restrict__ off) {
    __shared__ int red[256];
    int b = blockIdx.x, t = threadIdx.x;
    int base = b * SCAN_CHUNK;
    int end = base + SCAN_CHUNK; if (end > N_NODES) end = N_NODES;
    int n0 = base + 2 * t, n1 = n0 + 1;
    int d0 = (n0 < end) ? deg[n0] : 0;
    int d1 = (n1 < end) ? deg[n1] : 0;
    int mine = d0 + d1;
    red[t] = mine; __syncthreads();
    for (int d = 1; d < 256; d <<= 1) {
        int x = (t >= d) ? red[t - d] : 0; __syncthreads();
        red[t] += x; __syncthreads();
    }
    int excl = red[t] - mine + bbase[b];
    if (n0 < end) off[n0] = excl;
    if (n1 < end) off[n1] = excl + d0;
}

// atomic-free fill: position = off[dst] + chunk-base + rank
__global__ __launch_bounds__(256) void k_fill(const int* __restrict__ ei,
                                              const int* __restrict__ off,
                                              const int* __restrict__ degC,
                                              const int* __restrict__ rank,
                                              int* __restrict__ csr_src) {
    int e = blockIdx.x * 256 + threadIdx.x;
    if (e < N_EDGES) {
        int chunk = e / CHUNK_E;     // constant division -> magic mul
        int dst = ei[N_EDGES + e];
        csr_src[off[dst] + degC[(size_t)chunk * N_NODES + dst] + rank[e]] = ei[e];
    }
}

// ------- weight transpose + fp32->bf16: Wt[mat][n*128+k] = bf16(W[mat][k*128+n])
__global__ __launch_bounds__(256) void k_tw(const float* __restrict__ w1,
                                            const float* __restrict__ w2,
                                            const float* __restrict__ lw1,
                                            const float* __restrict__ lw2,
                                            unsigned short* __restrict__ Wt) {
    int bid = blockIdx.x;                     // 512 blocks
    int mat = bid >> 6;
    int t = (bid & 63) * 256 + threadIdx.x;   // 0..16383
    int k = t >> 7, n = t & 127;
    const float* src;
    if (mat == 0) src = w1;
    else if (mat == 1) src = w2;
    else if (mat < 5) src = lw1 + (size_t)(mat - 2) * 16384;
    else src = lw2 + (size_t)(mat - 5) * 16384;
    Wt[(size_t)mat * 16384 + n * 128 + k] = f2b_rne(src[t]);
}

// ---------------- aggregation: A[dst] = H[dst] + sum_{src in N(dst)} H[src] --
// one wave per dst; 16 lanes x 16B per row => 4 rows/load-instr; main loop 8
// rows in flight; tail is ONE masked batch of 32. Proven config: 256 threads,
// VGPR 44, 107us @ 3.69 TB/s L2-miss/fabric traffic (H 25.6MB >> 4MB per-XCD
// L2, so the gather runs over the L3 fabric; ~59% of the 6.3 TB/s streaming
// ceiling with random 2-line requests). R2: fusing MFMA behind it regresses.
// R4: capping VGPR below 44 spills (WRITE 25->261MB). Do not touch.
__global__ __launch_bounds__(256) void k_agg(const uint4* __restrict__ H4,
                                             const int* __restrict__ off,
                                             const int* __restrict__ csr_src,
                                             uint4* __restrict__ A4) {
    int wave = threadIdx.x >> 6;
    int lane = threadIdx.x & 63;
    int g4 = lane >> 4;        // neighbor sub-slot 0..3
    int c = lane & 15;         // uint4 index within 256B row
    int dst = blockIdx.x * 4 + wave;
    if (dst >= N_NODES) return;
    int s = off[dst], e = off[dst + 1];

    float acc[8];
    {
        uint4 h = H4[(size_t)dst * 16 + c];
        if (g4 == 0) {
            acc[0] = lo2f(h.x); acc[1] = hi2f(h.x);
            acc[2] = lo2f(h.y); acc[3] = hi2f(h.y);
            acc[4] = lo2f(h.z); acc[5] = hi2f(h.z);
            acc[6] = lo2f(h.w); acc[7] = hi2f(h.w);
        } else {
#pragma unroll
            for (int j = 0; j < 8; ++j) acc[j] = 0.f;
        }
    }

#define ADD8(v) do { \
        acc[0] += lo2f((v).x); acc[1] += hi2f((v).x); \
        acc[2] += lo2f((v).y); acc[3] += hi2f((v).y); \
        acc[4] += lo2f((v).z); acc[5] += hi2f((v).z); \
        acc[6] += lo2f((v).w); acc[7] += hi2f((v).w); } while (0)

    int i = s;
    for (; i + 32 <= e; i += 32) {
        int i0 = i + g4;
        int s0 = csr_src[i0];
        int s1 = csr_src[i0 + 4];
        int s2 = csr_src[i0 + 8];
        int s3 = csr_src[i0 + 12];
        int s4 = csr_src[i0 + 16];
        int s5 = csr_src[i0 + 20];
        int s6 = csr_src[i0 + 24];
        int s7 = csr_src[i0 + 28];
        uint4 v0 = H4[(size_t)s0 * 16 + c];
        uint4 v1 = H4[(size_t)s1 * 16 + c];
        uint4 v2 = H4[(size_t)s2 * 16 + c];
        uint4 v3 = H4[(size_t)s3 * 16 + c];
        uint4 v4 = H4[(size_t)s4 * 16 + c];
        uint4 v5 = H4[(size_t)s5 * 16 + c];
        uint4 v6 = H4[(size_t)s6 * 16 + c];
        uint4 v7 = H4[(size_t)s7 * 16 + c];
        ADD8(v0); ADD8(v1); ADD8(v2); ADD8(v3);
        ADD8(v4); ADD8(v5); ADD8(v6); ADD8(v7);
    }
    if (i < e) {               // single masked batch, full 8-deep MLP
        int last = e - 1;
        int i0 = i + g4;
        int x0 = i0,      x1 = i0 + 4,  x2 = i0 + 8,  x3 = i0 + 12;
        int x4i = i0 + 16, x5 = i0 + 20, x6 = i0 + 24, x7 = i0 + 28;
        int s0 = csr_src[x0 < e ? x0 : last];
        int s1 = csr_src[x1 < e ? x1 : last];
        int s2 = csr_src[x2 < e ? x2 : last];
        int s3 = csr_src[x3 < e ? x3 : last];
        int s4 = csr_src[x4i < e ? x4i : last];
        int s5 = csr_src[x5 < e ? x5 : last];
        int s6 = csr_src[x6 < e ? x6 : last];
        int s7 = csr_src[x7 < e ? x7 : last];
        uint4 v0 = H4[(size_t)s0 * 16 + c];
        uint4 v1 = H4[(size_t)s1 * 16 + c];
        uint4 v2 = H4[(size_t)s2 * 16 + c];
        uint4 v3 = H4[(size_t)s3 * 16 + c];
        uint4 v4 = H4[(size_t)s4 * 16 + c];
        uint4 v5 = H4[(size_t)s5 * 16 + c];
        uint4 v6 = H4[(size_t)s6 * 16 + c];
        uint4 v7 = H4[(size_t)s7 * 16 + c];
        if (x0 < e) ADD8(v0);
        if (x1 < e) ADD8(v1);
        if (x2 < e) ADD8(v2);
        if (x3 < e) ADD8(v3);
        if (x4i < e) ADD8(v4);
        if (x5 < e) ADD8(v5);
        if (x6 < e) ADD8(v6);
        if (x7 < e) ADD8(v7);
    }
#undef ADD8

#pragma unroll
    for (int j = 0; j < 8; ++j) {
        acc[j] += __shfl_xor(acc[j], 16, 64);
        acc[j] += __shfl_xor(acc[j], 32, 64);
    }
    if (g4 == 0) {
        uint4 o;
        o.x = (unsigned int)f2b_rne(acc[0]) | ((unsigned int)f2b_rne(acc[1]) << 16);
        o.y = (unsigned int)f2b_rne(acc[2]) | ((unsigned int)f2b_rne(acc[3]) << 16);
        o.z = (unsigned int)f2b_rne(acc[4]) | ((unsigned int)f2b_rne(acc[5]) << 16);
        o.w = (unsigned int)f2b_rne(acc[6]) | ((unsigned int)f2b_rne(acc[7]) << 16);
        A4[(size_t)dst * 16 + c] = o;
    }
}

// ------- MFMA GEMM 1: Yb = bf16(A @ W1 + b1), fused BN column stats ---------
__global__ __launch_bounds__(256) void k_mm1(const unsigned short* __restrict__ A,
                                             const unsigned short* __restrict__ Wt,
                                             const float* __restrict__ bias,
                                             unsigned short* __restrict__ Yb,
                                             float* __restrict__ partials) {
    __shared__ float sWS[4 * 128];
    __shared__ float s2WS[4 * 128];
    int wave = threadIdx.x >> 6, lane = threadIdx.x & 63;
    int quad = lane >> 4, l16 = lane & 15;
    int mload = blockIdx.x * 64 + wave * 16 + l16;      // < N_PAD

    short8 a[4];
    const unsigned short* arow = A + (size_t)mload * 128 + quad * 8;
#pragma unroll
    for (int kc = 0; kc < 4; ++kc) a[kc] = *(const short8*)(arow + kc * 32);

    floatx4 acc[8];
#pragma unroll
    for (int nt = 0; nt < 8; ++nt) {
        floatx4 z = {0.f, 0.f, 0.f, 0.f};
        acc[nt] = z;
        const unsigned short* wrow = Wt + (size_t)(nt * 16 + l16) * 128 + quad * 8;
#pragma unroll
        for (int kc = 0; kc < 4; ++kc) {
            short8 b = *(const short8*)(wrow + kc * 32);
            acc[nt] = __builtin_amdgcn_mfma_f32_16x16x32_bf16(a[kc], b, acc[nt], 0, 0, 0);
        }
    }

    int mrow0 = blockIdx.x * 64 + wave * 16 + quad * 4;
    float s_nt[8], s2_nt[8];
#pragma unroll
    for (int nt = 0; nt < 8; ++nt) {
        int n = nt * 16 + l16;
        float bn = bias[n];
        float s = 0.f, s2 = 0.f;
#pragma unroll
        for (int r = 0; r < 4; ++r) {
            int mm = mrow0 + r;
            if (mm < N_NODES) {
                float val = acc[nt][r] + bn;
                Yb[(size_t)mm * 128 + n] = f2b_rne(val);
                s += val;
                s2 = fmaf(val, val, s2);
            }
        }
        s_nt[nt] = s; s2_nt[nt] = s2;
    }
#pragma unroll
    for (int nt = 0; nt < 8; ++nt) {
        s_nt[nt] += __shfl_xor(s_nt[nt], 16, 64);
        s_nt[nt] += __shfl_xor(s_nt[nt], 32, 64);
        s2_nt[nt] += __shfl_xor(s2_nt[nt], 16, 64);
        s2_nt[nt] += __shfl_xor(s2_nt[nt], 32, 64);
    }
    if (quad == 0) {
#pragma unroll
        for (int nt = 0; nt < 8; ++nt) {
            sWS[wave * 128 + nt * 16 + l16] = s_nt[nt];
            s2WS[wave * 128 + nt * 16 + l16] = s2_nt[nt];
        }
    }
    __syncthreads();
    int tid = threadIdx.x;
    if (tid < 128) {
        float v = sWS[tid] + sWS[128 + tid] + sWS[256 + tid] + sWS[384 + tid];
        partials[(size_t)blockIdx.x * 256 + tid] = v;
    } else {
        int cc = tid - 128;
        float v = s2WS[cc] + s2WS[128 + cc] + s2WS[256 + cc] + s2WS[384 + cc];
        partials[(size_t)blockIdx.x * 256 + 128 + cc] = v;
    }
}

// ---- merged partial-reduce + BN finalize (last-block pattern) --------------
// 64 blocks strided-reduce partials -> pred rows; last finishing block sums
// the 64 pred rows (agent-scope loads bypass non-coherent per-XCD L2s) and
// writes stats. Removes the 1-block k_finalize launch from the critical path.
__global__ __launch_bounds__(256) void k_redfin(const float* __restrict__ partials,
                                                float* __restrict__ pred,
                                                float* __restrict__ stats,
                                                const float* __restrict__ g,
                                                const float* __restrict__ be,
                                                int* __restrict__ ctr) {
    __shared__ float red[256];
    __shared__ int sLast;
    int b = blockIdx.x, tid = threadIdx.x;
    float s = 0.f;
    for (int r = b; r < MM_BLOCKS; r += RED_BLOCKS) s += partials[(size_t)r * 256 + tid];
    pred[(size_t)b * 256 + tid] = s;
    __threadfence();                               // release pred row (device scope)
    if (tid == 0) sLast = (atomicAdd(ctr, 1) == RED_BLOCKS - 1);
    __syncthreads();
    if (!sLast) return;

    __threadfence();                               // acquire side
    float t = 0.f;
#pragma unroll 8
    for (int bb = 0; bb < RED_BLOCKS; ++bb)
        t += __hip_atomic_load(&pred[(size_t)bb * 256 + tid],
                               __ATOMIC_RELAXED, __HIP_MEMORY_SCOPE_AGENT);
    red[tid] = t;
    __syncthreads();
    if (tid < 128) {
        float sum = red[tid], sumsq = red[128 + tid];
        const float invN = 1.f / (float)N_NODES;
        float m = sum * invN;
        float v = sumsq * invN - m * m;
        float rstd = rsqrtf(v + BN_EPS);
        float sca = g[tid] * rstd;
        stats[tid] = sca;
        stats[128 + tid] = be[tid] - m * sca;
    }
    if (tid == 0) *ctr = 0;                        // re-arm for next layer
}

// ---- MFMA GEMM 2: H = relu( relu(Yb*sc+sh) @ W2 + b2 ), bf16 in/out --------
__global__ __launch_bounds__(256) void k_mm2(const unsigned short* __restrict__ Yb,
                                             const unsigned short* __restrict__ Wt,
                                             const float* __restrict__ bias,
                                             const float* __restrict__ stats,
                                             unsigned short* __restrict__ Hb) {
    int wave = threadIdx.x >> 6, lane = threadIdx.x & 63;
    int quad = lane >> 4, l16 = lane & 15;
    int mload = blockIdx.x * 64 + wave * 16 + l16;

    const unsigned short* yrow = Yb + (size_t)mload * 128;
    short8 a[4];
#pragma unroll
    for (int kc = 0; kc < 4; ++kc) {
        int k0 = kc * 32 + quad * 8;
        union { short8 s8; unsigned short u[8]; } q, p;
        q.s8 = *(const short8*)(yrow + k0);
#pragma unroll
        for (int j = 0; j < 8; ++j) {
            float sc = stats[k0 + j];
            float sh = stats[128 + k0 + j];
            float t = fmaxf(fmaf(bits2f(q.u[j]), sc, sh), 0.f);
            p.u[j] = f2b_rne(t);
        }
        a[kc] = p.s8;
    }

    floatx4 acc[8];
#pragma unroll
    for (int nt = 0; nt < 8; ++nt) {
        floatx4 z = {0.f, 0.f, 0.f, 0.f};
        acc[nt] = z;
        const unsigned short* wrow = Wt + (size_t)(nt * 16 + l16) * 128 + quad * 8;
#pragma unroll
        for (int kc = 0; kc < 4; ++kc) {
            short8 b = *(const short8*)(wrow + kc * 32);
            acc[nt] = __builtin_amdgcn_mfma_f32_16x16x32_bf16(a[kc], b, acc[nt], 0, 0, 0);
        }
    }

    int mrow0 = blockIdx.x * 64 + wave * 16 + quad * 4;
#pragma unroll
    for (int nt = 0; nt < 8; ++nt) {
        int n = nt * 16 + l16;
        float bn = bias[n];
#pragma unroll
        for (int r = 0; r < 4; ++r) {
            int mm = mrow0 + r;
            if (mm < N_NODES) {
                float h = fmaxf(acc[nt][r] + bn, 0.f);
                Hb[(size_t)mm * 128 + n] = f2b_rne(h);
            }
        }
    }
}

// ------- global add pool (bf16 in, fp32 out), 2 row-halves x 128 cols -------
__global__ __launch_bounds__(256) void k_pool(const unsigned short* __restrict__ Hb,
                                              const int* __restrict__ startv,
                                              const int* __restrict__ endv,
                                              float* __restrict__ gr, int loff) {
    __shared__ float part[128];
    int g = blockIdx.x;
    int tid = threadIdx.x;
    int c = tid & 127, half = tid >> 7;      // half 0: even rows, half 1: odd rows
    int s = startv[g], e = endv[g];
    float acc = 0.f;
    int r = s + half;
    for (; r + 7 <= e; r += 8) {             // rows r, r+2, r+4, r+6 all < e
        unsigned short a0 = Hb[(size_t)r * 128 + c];
        unsigned short a1 = Hb[(size_t)(r + 2) * 128 + c];
        unsigned short a2 = Hb[(size_t)(r + 4) * 128 + c];
        unsigned short a3 = Hb[(size_t)(r + 6) * 128 + c];
        acc += bits2f(a0) + bits2f(a1) + bits2f(a2) + bits2f(a3);
    }
    for (; r < e; r += 2) acc += bits2f(Hb[(size_t)r * 128 + c]);
    if (half) part[c] = acc;
    __syncthreads();
    if (!half) gr[(size_t)g * (4 * DIM) + loff + c] = acc + part[c];
}

// ---------------- classifier (fp32 weights, fp32 out) ----------------

__global__ __launch_bounds__(128) void k_cls1(const float* __restrict__ gr,
                                              const float* __restrict__ w,
                                              const float* __restrict__ b,
                                              float* __restrict__ out) {
    __shared__ float row[512];
    int g = blockIdx.x, tid = threadIdx.x;
    for (int i = tid; i < 512; i += 128) row[i] = gr[(size_t)g * 512 + i];
    __syncthreads();
    float acc = b[tid];
    for (int k = 0; k < 512; ++k) acc = fmaf(row[k], w[k * 128 + tid], acc);
    out[(size_t)g * 128 + tid] = fmaxf(acc, 0.f);
}

__global__ __launch_bounds__(64) void k_cls2(const float* __restrict__ gr1,
                                             const float* __restrict__ w,
                                             const float* __restrict__ b,
                                             float* __restrict__ out) {
    __shared__ float row[128];
    int g = blockIdx.x, tid = threadIdx.x;
    row[tid] = gr1[(size_t)g * 128 + tid];
    row[tid + 64] = gr1[(size_t)g * 128 + tid + 64];
    __syncthreads();
    float acc = b[tid];
    for (int k = 0; k < 128; ++k) acc = fmaf(row[k], w[k * 64 + tid], acc);
    out[(size_t)g * 64 + tid] = fmaxf(acc, 0.f);
}

__global__ __launch_bounds__(256) void k_cls3(const float* __restrict__ gr2,
                                              const float* __restrict__ w,
                                              const float* __restrict__ b,
                                              float* __restrict__ out) {
    int idx = blockIdx.x * 256 + threadIdx.x;
    if (idx < N_GRAPHS * 2) {
        int g = idx >> 1, j = idx & 1;
        float acc = b[j];
        const float* r = gr2 + (size_t)g * 64;
        for (int k = 0; k < 64; ++k) acc = fmaf(r[k], w[k * 2 + j], acc);
        out[idx] = acc;
    }
}

// ---------------- launch ----------------

extern "C" void kernel_launch(void* const* d_in, const int* in_sizes, int n_in,
                              void* d_out, int out_size, void* d_ws, size_t ws_size,
                              hipStream_t stream) {
    const float* x = (const float*)d_in[0];
    const int* ei = (const int*)d_in[1];
    const int* batch = (const int*)d_in[2];
    const float* b1 = (const float*)d_in[4];
    const float* g1 = (const float*)d_in[5];
    const float* be1 = (const float*)d_in[6];
    const float* b2 = (const float*)d_in[8];
    const float* lb1 = (const float*)d_in[10];
    const float* lg1 = (const float*)d_in[11];
    const float* lbe1 = (const float*)d_in[12];
    const float* lb2 = (const float*)d_in[14];
    const float* cw1 = (const float*)d_in[15];
    const float* cb1 = (const float*)d_in[16];
    const float* cw2 = (const float*)d_in[17];
    const float* cb2 = (const float*)d_in[18];
    const float* cw3 = (const float*)d_in[19];
    const float* cb3 = (const float*)d_in[20];

    // workspace layout (float units; every segment 16B-aligned)
    float* ws = (float*)d_ws;
    unsigned short* Yb = (unsigned short*)ws;                     // N_PAD*128 bf16
    float* gr = ws + (size_t)N_PAD * 64;                          // 1024*512
    float* gr1 = gr + (size_t)N_GRAPHS * 512;                     // 1024*128
    float* gr2 = gr1 + (size_t)N_GRAPHS * 128;                    // 1024*64
    float* stats = gr2 + (size_t)N_GRAPHS * 64;                   // 256
    float* partials = stats + 256;                                // 1563*256
    float* pred = partials + (size_t)MM_BLOCKS * 256;             // 64*256
    float* p_end = pred + (size_t)RED_BLOCKS * 256;
    int* startv = (int*)p_end;
    int* endv = startv + N_GRAPHS;
    unsigned short* Wt = (unsigned short*)(endv + N_GRAPHS);      // 8*16384 bf16
    unsigned short* A = Wt + (size_t)8 * 16384;                   // N_PAD*128 bf16
    unsigned short* Hb0 = A + (size_t)N_PAD * 128;                // bf16(x)
    unsigned short* Hb1 = Hb0 + (size_t)N_NODES * 128;            // layer H
    int* degC = (int*)(Hb1 + (size_t)N_NODES * 128);              // NCHUNK*N_NODES
    int* deg = degC + (size_t)NCHUNK * N_NODES;                   // N_NODES
    int* rank = deg + N_NODES;                                    // N_EDGES
    int* offarr = rank + N_EDGES;                                 // N_NODES+1
    int* csr_src = offarr + (N_NODES + 4);                        // N_EDGES
    int* bsum = csr_src + N_EDGES;                                // 256
    int* bbase = bsum + 256;                                      // 256
    int* ctr = bbase + 256;                                       // 1 (redfin counter)

    k_cvt0<<<12500, 256, 0, stream>>>((const float4*)x, (ushort4*)Hb0);
    k_binit<<<4, 256, 0, stream>>>(startv, endv, ctr);
    k_bounds<<<(N_NODES + 255) / 256, 256, 0, stream>>>(batch, startv, endv);
    k_deg2<<<NCHUNK * NRANGES, 256, 0, stream>>>(ei, degC, rank);
    k_comb<<<(N_NODES + 255) / 256, 256, 0, stream>>>(degC, deg);
    k_scanA<<<256, 256, 0, stream>>>(deg, bsum);
    k_scanB<<<1, 256, 0, stream>>>(bsum, bbase, &offarr[N_NODES]);
    k_scanC<<<256, 256, 0, stream>>>(deg, bbase, offarr);
    k_fill<<<N_EDGES / 256, 256, 0, stream>>>(ei, offarr, degC, rank, csr_src);
    k_tw<<<512, 256, 0, stream>>>((const float*)d_in[3], (const float*)d_in[7],
                                  (const float*)d_in[9], (const float*)d_in[13], Wt);

    for (int l = 0; l < 4; ++l) {
        const unsigned short* aggIn = (l == 0) ? Hb0 : Hb1;

        const unsigned short* W1t = Wt + (size_t)((l == 0) ? 0 : (1 + l)) * 16384;
        const unsigned short* W2t = Wt + (size_t)((l == 0) ? 1 : (4 + l)) * 16384;
        const float* B1 = (l == 0) ? b1 : lb1 + (size_t)(l - 1) * 128;
        const float* B2 = (l == 0) ? b2 : lb2 + (size_t)(l - 1) * 128;
        const float* G = (l == 0) ? g1 : lg1 + (size_t)(l - 1) * 128;
        const float* BE = (l == 0) ? be1 : lbe1 + (size_t)(l - 1) * 128;

        k_agg<<<N_NODES / 4, 256, 0, stream>>>((const uint4*)aggIn, offarr, csr_src,
                                               (uint4*)A);
        k_mm1<<<MM_BLOCKS, 256, 0, stream>>>(A, W1t, B1, Yb, partials);
        k_redfin<<<RED_BLOCKS, 256, 0, stream>>>(partials, pred, stats, G, BE, ctr);
        k_mm2<<<MM_BLOCKS, 256, 0, stream>>>(Yb, W2t, B2, stats, Hb1);
        k_pool<<<N_GRAPHS, 256, 0, stream>>>(Hb1, startv, endv, gr, l * DIM);
    }

    k_cls1<<<N_GRAPHS, 128, 0, stream>>>(gr, cw1, cb1, gr1);
    k_cls2<<<N_GRAPHS, 64, 0, stream>>>(gr1, cw2, cb2, gr2);
    k_cls3<<<8, 256, 0, stream>>>(gr2, cw3, cb3, (float*)d_out);
}

// Round 6
// 1190.814 us; speedup vs baseline: 1.2401x; 1.0169x over previous
//
#include <hip/hip_runtime.h>
#include <hip/hip_bf16.h>

#define N_NODES 100000
#define N_PAD 100032          // 1563 * 64
#define MM_BLOCKS 1563        // N_PAD / 64
#define RED_BLOCKS 64
#define N_EDGES 3200000
#define N_GRAPHS 1024
#define DIM 128
#define BN_EPS 1e-5f
#define SCAN_CHUNK 391        // 256 * 391 = 100096 >= N_NODES
#define AGG_BLOCKS 25000      // N_NODES / 4

// CSR build: LDS-histogram counting sort (no global atomics)
#define NCHUNK 32             // edge chunks; 32 * 100000 = N_EDGES exactly
#define CHUNK_E 100000
#define R_NODES 16384         // 16384 * 4B = 64 KB LDS histogram
#define NRANGES 7             // 7 * 16384 = 114688 >= N_NODES

typedef __attribute__((ext_vector_type(8))) short short8;
typedef __attribute__((ext_vector_type(4))) float floatx4;

__device__ __forceinline__ float bits2f(unsigned short u) {
    return __uint_as_float(((unsigned int)u) << 16);
}
__device__ __forceinline__ unsigned short f2b_rne(float f) {
    unsigned int u = __float_as_uint(f);
    unsigned int r = u + 0x7FFFu + ((u >> 16) & 1u);
    return (unsigned short)(r >> 16);
}
__device__ __forceinline__ float lo2f(unsigned int u) { return __uint_as_float(u << 16); }
__device__ __forceinline__ float hi2f(unsigned int u) { return __uint_as_float(u & 0xFFFF0000u); }

// ------- x (fp32) -> bf16 Hb0, vectorized; blocks 0-3 also zero startv/endv/ctr
__global__ __launch_bounds__(256) void k_cvt0(const float4* __restrict__ x4,
                                              ushort4* __restrict__ o4,
                                              int* __restrict__ startv,
                                              int* __restrict__ endv,
                                              int* __restrict__ ctr) {
    if (blockIdx.x < 4) {
        int j = blockIdx.x * 256 + threadIdx.x;
        startv[j] = 0; endv[j] = 0;
        if (j < 2) ctr[j] = 0;
    }
    size_t i = (size_t)blockIdx.x * 256 + threadIdx.x;   // exactly 3,200,000
    float4 v = x4[i];
    ushort4 o;
    o.x = f2b_rne(v.x); o.y = f2b_rne(v.y); o.z = f2b_rne(v.z); o.w = f2b_rne(v.w);
    o4[i] = o;
}

// ---------------- CSR degree histogram + graph bounds (merged grid) ---------
// blocks [0,224): deg2 LDS-histogram role; blocks [224,615): bounds role.
__global__ __launch_bounds__(256) void k_deg2b(const int* __restrict__ ei,
                                               int* __restrict__ degC,   // [NCHUNK][N_NODES]
                                               int* __restrict__ rank,
                                               const int* __restrict__ batch,
                                               int* __restrict__ startv,
                                               int* __restrict__ endv) {
    __shared__ int hist[R_NODES];
    if ((int)blockIdx.x >= NCHUNK * NRANGES) {           // ---- bounds role ----
        int i = ((int)blockIdx.x - NCHUNK * NRANGES) * 256 + threadIdx.x;
        if (i >= N_NODES) return;
        int g = batch[i];
        if (i == 0 || batch[i - 1] != g) startv[g] = i;
        if (i == N_NODES - 1 || batch[i + 1] != g) endv[g] = i + 1;
        return;
    }
    // ---- deg2 role ----
    int chunk = blockIdx.x / NRANGES;
    int range = blockIdx.x - chunk * NRANGES;
    int base = range * R_NODES;
    for (int i = threadIdx.x; i < R_NODES; i += 256) hist[i] = 0;
    __syncthreads();

    const int4* d4 = (const int4*)(ei + N_EDGES + chunk * CHUNK_E);
    int* rk = rank + chunk * CHUNK_E;
    const int niter = CHUNK_E / 4;   // 25000
    for (int i = threadIdx.x; i < niter; i += 256) {
        int4 d = d4[i];
        unsigned int r0 = (unsigned int)(d.x - base);
        unsigned int r1 = (unsigned int)(d.y - base);
        unsigned int r2 = (unsigned int)(d.z - base);
        unsigned int r3 = (unsigned int)(d.w - base);
        if (r0 < R_NODES) rk[4 * i]     = atomicAdd(&hist[r0], 1);
        if (r1 < R_NODES) rk[4 * i + 1] = atomicAdd(&hist[r1], 1);
        if (r2 < R_NODES) rk[4 * i + 2] = atomicAdd(&hist[r2], 1);
        if (r3 < R_NODES) rk[4 * i + 3] = atomicAdd(&hist[r3], 1);
    }
    __syncthreads();

    int top = N_NODES - base; if (top > R_NODES) top = R_NODES;
    int* dC = degC + (size_t)chunk * N_NODES + base;
    for (int i = threadIdx.x; i < top; i += 256) dC[i] = hist[i];
}

// per-node exclusive prefix over the NCHUNK copies, in place; total degree out
__global__ __launch_bounds__(256) void k_comb(int* __restrict__ degC,
                                              int* __restrict__ deg) {
    int i = blockIdx.x * 256 + threadIdx.x;
    if (i >= N_NODES) return;
    int v[NCHUNK];
#pragma unroll
    for (int c = 0; c < NCHUNK; ++c) v[c] = degC[(size_t)c * N_NODES + i];
    int run = 0;
#pragma unroll
    for (int c = 0; c < NCHUNK; ++c) {
        degC[(size_t)c * N_NODES + i] = run;
        run += v[c];
    }
    deg[i] = run;
}

// scanA + scanB merged (last-block pattern, proven by R5's redfin):
// 256 blocks write bsum[b]; last finishing block scans the 256 sums.
__global__ __launch_bounds__(256) void k_scanAB(const int* __restrict__ deg,
                                                int* __restrict__ bsum,
                                                int* __restrict__ bbase,
                                                int* __restrict__ offend,
                                                int* __restrict__ ctr) {
    __shared__ int red[256];
    __shared__ int v[256];
    __shared__ int sLast;
    int b = blockIdx.x, t = threadIdx.x;
    int base = b * SCAN_CHUNK;
    int end = base + SCAN_CHUNK; if (end > N_NODES) end = N_NODES;
    int s = 0;
    for (int i = base + t; i < end; i += 256) s += deg[i];
    red[t] = s; __syncthreads();
    for (int st = 128; st > 0; st >>= 1) { if (t < st) red[t] += red[t + st]; __syncthreads(); }
    if (t == 0) {
        bsum[b] = red[0];
        __threadfence();
        sLast = (atomicAdd(ctr, 1) == 255);
    }
    __syncthreads();
    if (!sLast) return;

    __threadfence();
    int mine = __hip_atomic_load(&bsum[t], __ATOMIC_RELAXED, __HIP_MEMORY_SCOPE_AGENT);
    v[t] = mine; __syncthreads();
    for (int d = 1; d < 256; d <<= 1) {
        int x = (t >= d) ? v[t - d] : 0; __syncthreads();
        v[t] += x; __syncthreads();
    }
    bbase[t] = v[t] - mine;
    if (t == 255) *offend = v[255];
}

__global__ __launch_bounds__(256) void k_scanC(const int* __restrict__ deg,
                                               const int* __restrict__ bbase,
                                               int* __restrict__ off) {
    __shared__ int red[256];
    int b = blockIdx.x, t = threadIdx.x;
    int base = b * SCAN_CHUNK;
    int end = base + SCAN_CHUNK; if (end > N_NODES) end = N_NODES;
    int n0 = base + 2 * t, n1 = n0 + 1;
    int d0 = (n0 < end) ? deg[n0] : 0;
    int d1 = (n1 < end) ? deg[n1] : 0;
    int mine = d0 + d1;
    red[t] = mine; __syncthreads();
    for (int d = 1; d < 256; d <<= 1) {
        int x = (t >= d) ? red[t - d] : 0; __syncthreads();
        red[t] += x; __syncthreads();
    }
    int excl = red[t] - mine + bbase[b];
    if (n0 < end) off[n0] = excl;
    if (n1 < end) off[n1] = excl + d0;
}

// ---- CSR fill + weight transpose (merged grid: [0,12500) fill, then 512 tw)
__global__ __launch_bounds__(256) void k_filltw(const int* __restrict__ ei,
                                                const int* __restrict__ off,
                                                const int* __restrict__ degC,
                                                const int* __restrict__ rank,
                                                int* __restrict__ csr_src,
                                                const float* __restrict__ w1,
                                                const float* __restrict__ w2,
                                                const float* __restrict__ lw1,
                                                const float* __restrict__ lw2,
                                                unsigned short* __restrict__ Wt) {
    int bid = blockIdx.x;
    if (bid >= N_EDGES / 256) {                          // ---- tw role ----
        int b2 = bid - N_EDGES / 256;                    // 0..511
        int mat = b2 >> 6;
        int t = (b2 & 63) * 256 + threadIdx.x;           // 0..16383
        int k = t >> 7, n = t & 127;
        const float* src;
        if (mat == 0) src = w1;
        else if (mat == 1) src = w2;
        else if (mat < 5) src = lw1 + (size_t)(mat - 2) * 16384;
        else src = lw2 + (size_t)(mat - 5) * 16384;
        Wt[(size_t)mat * 16384 + n * 128 + k] = f2b_rne(src[t]);
        return;
    }
    // ---- fill role: position = off[dst] + chunk-base + rank ----
    int e = bid * 256 + threadIdx.x;
    if (e < N_EDGES) {
        int chunk = e / CHUNK_E;     // constant division -> magic mul
        int dst = ei[N_EDGES + e];
        csr_src[off[dst] + degC[(size_t)chunk * N_NODES + dst] + rank[e]] = ei[e];
    }
}

// ====== aggregation (+ optional pooled tail blocks) =========================
// Blocks [0, AGG_BLOCKS): A[dst] = H[dst] + sum_{src in N(dst)} H[src].
// Proven config (256 thr, VGPR 44, 107us, 3.69 TB/s); body untouched (R2: no
// MFMA fusion; R4: no VGPR caps). Blocks [AGG_BLOCKS, +N_GRAPHS): global-add
// pool of the PREVIOUS layer's H -- pure reads of the same Hb the agg gathers
// from (no dependence), dispatched last so they fill CUs during agg's drain
// tail. 3 launches removed, ~10us/layer of pool work hidden under agg.
__global__ __launch_bounds__(256) void k_aggpool(const uint4* __restrict__ H4,
                                                 const int* __restrict__ off,
                                                 const int* __restrict__ csr_src,
                                                 uint4* __restrict__ A4,
                                                 const unsigned short* __restrict__ Hbp,
                                                 const int* __restrict__ startv,
                                                 const int* __restrict__ endv,
                                                 float* __restrict__ gr, int loff) {
    __shared__ float part[128];
    if ((int)blockIdx.x >= AGG_BLOCKS) {                 // ---- pool role ----
        int g = (int)blockIdx.x - AGG_BLOCKS;
        int tid = threadIdx.x;
        int c = tid & 127, half = tid >> 7;              // even/odd row halves
        int s = startv[g], e = endv[g];
        float acc = 0.f;
        int r = s + half;
        for (; r + 7 <= e; r += 8) {
            unsigned short a0 = Hbp[(size_t)r * 128 + c];
            unsigned short a1 = Hbp[(size_t)(r + 2) * 128 + c];
            unsigned short a2 = Hbp[(size_t)(r + 4) * 128 + c];
            unsigned short a3 = Hbp[(size_t)(r + 6) * 128 + c];
            acc += bits2f(a0) + bits2f(a1) + bits2f(a2) + bits2f(a3);
        }
        for (; r < e; r += 2) acc += bits2f(Hbp[(size_t)r * 128 + c]);
        if (half) part[c] = acc;
        __syncthreads();
        if (!half) gr[(size_t)g * (4 * DIM) + loff + c] = acc + part[c];
        return;
    }
    // ---- agg role (body identical to proven k_agg) ----
    int wave = threadIdx.x >> 6;
    int lane = threadIdx.x & 63;
    int g4 = lane >> 4;        // neighbor sub-slot 0..3
    int c = lane & 15;         // uint4 index within 256B row
    int dst = blockIdx.x * 4 + wave;
    if (dst >= N_NODES) return;
    int s = off[dst], e = off[dst + 1];

    float acc[8];
    {
        uint4 h = H4[(size_t)dst * 16 + c];
        if (g4 == 0) {
            acc[0] = lo2f(h.x); acc[1] = hi2f(h.x);
            acc[2] = lo2f(h.y); acc[3] = hi2f(h.y);
            acc[4] = lo2f(h.z); acc[5] = hi2f(h.z);
            acc[6] = lo2f(h.w); acc[7] = hi2f(h.w);
        } else {
#pragma unroll
            for (int j = 0; j < 8; ++j) acc[j] = 0.f;
        }
    }

#define ADD8(v) do { \
        acc[0] += lo2f((v).x); acc[1] += hi2f((v).x); \
        acc[2] += lo2f((v).y); acc[3] += hi2f((v).y); \
        acc[4] += lo2f((v).z); acc[5] += hi2f((v).z); \
        acc[6] += lo2f((v).w); acc[7] += hi2f((v).w); } while (0)

    int i = s;
    for (; i + 32 <= e; i += 32) {
        int i0 = i + g4;
        int s0 = csr_src[i0];
        int s1 = csr_src[i0 + 4];
        int s2 = csr_src[i0 + 8];
        int s3 = csr_src[i0 + 12];
        int s4 = csr_src[i0 + 16];
        int s5 = csr_src[i0 + 20];
        int s6 = csr_src[i0 + 24];
        int s7 = csr_src[i0 + 28];
        uint4 v0 = H4[(size_t)s0 * 16 + c];
        uint4 v1 = H4[(size_t)s1 * 16 + c];
        uint4 v2 = H4[(size_t)s2 * 16 + c];
        uint4 v3 = H4[(size_t)s3 * 16 + c];
        uint4 v4 = H4[(size_t)s4 * 16 + c];
        uint4 v5 = H4[(size_t)s5 * 16 + c];
        uint4 v6 = H4[(size_t)s6 * 16 + c];
        uint4 v7 = H4[(size_t)s7 * 16 + c];
        ADD8(v0); ADD8(v1); ADD8(v2); ADD8(v3);
        ADD8(v4); ADD8(v5); ADD8(v6); ADD8(v7);
    }
    if (i < e) {               // single masked batch, full 8-deep MLP
        int last = e - 1;
        int i0 = i + g4;
        int x0 = i0,      x1 = i0 + 4,  x2 = i0 + 8,  x3 = i0 + 12;
        int x4i = i0 + 16, x5 = i0 + 20, x6 = i0 + 24, x7 = i0 + 28;
        int s0 = csr_src[x0 < e ? x0 : last];
        int s1 = csr_src[x1 < e ? x1 : last];
        int s2 = csr_src[x2 < e ? x2 : last];
        int s3 = csr_src[x3 < e ? x3 : last];
        int s4 = csr_src[x4i < e ? x4i : last];
        int s5 = csr_src[x5 < e ? x5 : last];
        int s6 = csr_src[x6 < e ? x6 : last];
        int s7 = csr_src[x7 < e ? x7 : last];
        uint4 v0 = H4[(size_t)s0 * 16 + c];
        uint4 v1 = H4[(size_t)s1 * 16 + c];
        uint4 v2 = H4[(size_t)s2 * 16 + c];
        uint4 v3 = H4[(size_t)s3 * 16 + c];
        uint4 v4 = H4[(size_t)s4 * 16 + c];
        uint4 v5 = H4[(size_t)s5 * 16 + c];
        uint4 v6 = H4[(size_t)s6 * 16 + c];
        uint4 v7 = H4[(size_t)s7 * 16 + c];
        if (x0 < e) ADD8(v0);
        if (x1 < e) ADD8(v1);
        if (x2 < e) ADD8(v2);
        if (x3 < e) ADD8(v3);
        if (x4i < e) ADD8(v4);
        if (x5 < e) ADD8(v5);
        if (x6 < e) ADD8(v6);
        if (x7 < e) ADD8(v7);
    }
#undef ADD8

#pragma unroll
    for (int j = 0; j < 8; ++j) {
        acc[j] += __shfl_xor(acc[j], 16, 64);
        acc[j] += __shfl_xor(acc[j], 32, 64);
    }
    if (g4 == 0) {
        uint4 o;
        o.x = (unsigned int)f2b_rne(acc[0]) | ((unsigned int)f2b_rne(acc[1]) << 16);
        o.y = (unsigned int)f2b_rne(acc[2]) | ((unsigned int)f2b_rne(acc[3]) << 16);
        o.z = (unsigned int)f2b_rne(acc[4]) | ((unsigned int)f2b_rne(acc[5]) << 16);
        o.w = (unsigned int)f2b_rne(acc[6]) | ((unsigned int)f2b_rne(acc[7]) << 16);
        A4[(size_t)dst * 16 + c] = o;
    }
}

// ------- MFMA GEMM 1: Yb = bf16(A @ W1 + b1), fused BN column stats ---------
__global__ __launch_bounds__(256) void k_mm1(const unsigned short* __restrict__ A,
                                             const unsigned short* __restrict__ Wt,
                                             const float* __restrict__ bias,
                                             unsigned short* __restrict__ Yb,
                                             float* __restrict__ partials) {
    __shared__ float sWS[4 * 128];
    __shared__ float s2WS[4 * 128];
    int wave = threadIdx.x >> 6, lane = threadIdx.x & 63;
    int quad = lane >> 4, l16 = lane & 15;
    int mload = blockIdx.x * 64 + wave * 16 + l16;      // < N_PAD

    short8 a[4];
    const unsigned short* arow = A + (size_t)mload * 128 + quad * 8;
#pragma unroll
    for (int kc = 0; kc < 4; ++kc) a[kc] = *(const short8*)(arow + kc * 32);

    floatx4 acc[8];
#pragma unroll
    for (int nt = 0; nt < 8; ++nt) {
        floatx4 z = {0.f, 0.f, 0.f, 0.f};
        acc[nt] = z;
        const unsigned short* wrow = Wt + (size_t)(nt * 16 + l16) * 128 + quad * 8;
#pragma unroll
        for (int kc = 0; kc < 4; ++kc) {
            short8 b = *(const short8*)(wrow + kc * 32);
            acc[nt] = __builtin_amdgcn_mfma_f32_16x16x32_bf16(a[kc], b, acc[nt], 0, 0, 0);
        }
    }

    int mrow0 = blockIdx.x * 64 + wave * 16 + quad * 4;
    float s_nt[8], s2_nt[8];
#pragma unroll
    for (int nt = 0; nt < 8; ++nt) {
        int n = nt * 16 + l16;
        float bn = bias[n];
        float s = 0.f, s2 = 0.f;
#pragma unroll
        for (int r = 0; r < 4; ++r) {
            int mm = mrow0 + r;
            if (mm < N_NODES) {
                float val = acc[nt][r] + bn;
                Yb[(size_t)mm * 128 + n] = f2b_rne(val);
                s += val;
                s2 = fmaf(val, val, s2);
            }
        }
        s_nt[nt] = s; s2_nt[nt] = s2;
    }
#pragma unroll
    for (int nt = 0; nt < 8; ++nt) {
        s_nt[nt] += __shfl_xor(s_nt[nt], 16, 64);
        s_nt[nt] += __shfl_xor(s_nt[nt], 32, 64);
        s2_nt[nt] += __shfl_xor(s2_nt[nt], 16, 64);
        s2_nt[nt] += __shfl_xor(s2_nt[nt], 32, 64);
    }
    if (quad == 0) {
#pragma unroll
        for (int nt = 0; nt < 8; ++nt) {
            sWS[wave * 128 + nt * 16 + l16] = s_nt[nt];
            s2WS[wave * 128 + nt * 16 + l16] = s2_nt[nt];
        }
    }
    __syncthreads();
    int tid = threadIdx.x;
    if (tid < 128) {
        float v = sWS[tid] + sWS[128 + tid] + sWS[256 + tid] + sWS[384 + tid];
        partials[(size_t)blockIdx.x * 256 + tid] = v;
    } else {
        int cc = tid - 128;
        float v = s2WS[cc] + s2WS[128 + cc] + s2WS[256 + cc] + s2WS[384 + cc];
        partials[(size_t)blockIdx.x * 256 + 128 + cc] = v;
    }
}

// ---- merged partial-reduce + BN finalize (last-block pattern, proven R5) ---
__global__ __launch_bounds__(256) void k_redfin(const float* __restrict__ partials,
                                                float* __restrict__ pred,
                                                float* __restrict__ stats,
                                                const float* __restrict__ g,
                                                const float* __restrict__ be,
                                                int* __restrict__ ctr) {
    __shared__ float red[256];
    __shared__ int sLast;
    int b = blockIdx.x, tid = threadIdx.x;
    float s = 0.f;
    for (int r = b; r < MM_BLOCKS; r += RED_BLOCKS) s += partials[(size_t)r * 256 + tid];
    pred[(size_t)b * 256 + tid] = s;
    __threadfence();                               // release pred row (device scope)
    if (tid == 0) sLast = (atomicAdd(ctr, 1) == RED_BLOCKS - 1);
    __syncthreads();
    if (!sLast) return;

    __threadfence();                               // acquire side
    float t = 0.f;
#pragma unroll 8
    for (int bb = 0; bb < RED_BLOCKS; ++bb)
        t += __hip_atomic_load(&pred[(size_t)bb * 256 + tid],
                               __ATOMIC_RELAXED, __HIP_MEMORY_SCOPE_AGENT);
    red[tid] = t;
    __syncthreads();
    if (tid < 128) {
        float sum = red[tid], sumsq = red[128 + tid];
        const float invN = 1.f / (float)N_NODES;
        float m = sum * invN;
        float v = sumsq * invN - m * m;
        float rstd = rsqrtf(v + BN_EPS);
        float sca = g[tid] * rstd;
        stats[tid] = sca;
        stats[128 + tid] = be[tid] - m * sca;
    }
    if (tid == 0) *ctr = 0;                        // re-arm for next layer
}

// ---- MFMA GEMM 2: H = relu( relu(Yb*sc+sh) @ W2 + b2 ), bf16 in/out --------
__global__ __launch_bounds__(256) void k_mm2(const unsigned short* __restrict__ Yb,
                                             const unsigned short* __restrict__ Wt,
                                             const float* __restrict__ bias,
                                             const float* __restrict__ stats,
                                             unsigned short* __restrict__ Hb) {
    int wave = threadIdx.x >> 6, lane = threadIdx.x & 63;
    int quad = lane >> 4, l16 = lane & 15;
    int mload = blockIdx.x * 64 + wave * 16 + l16;

    const unsigned short* yrow = Yb + (size_t)mload * 128;
    short8 a[4];
#pragma unroll
    for (int kc = 0; kc < 4; ++kc) {
        int k0 = kc * 32 + quad * 8;
        union { short8 s8; unsigned short u[8]; } q, p;
        q.s8 = *(const short8*)(yrow + k0);
#pragma unroll
        for (int j = 0; j < 8; ++j) {
            float sc = stats[k0 + j];
            float sh = stats[128 + k0 + j];
            float t = fmaxf(fmaf(bits2f(q.u[j]), sc, sh), 0.f);
            p.u[j] = f2b_rne(t);
        }
        a[kc] = p.s8;
    }

    floatx4 acc[8];
#pragma unroll
    for (int nt = 0; nt < 8; ++nt) {
        floatx4 z = {0.f, 0.f, 0.f, 0.f};
        acc[nt] = z;
        const unsigned short* wrow = Wt + (size_t)(nt * 16 + l16) * 128 + quad * 8;
#pragma unroll
        for (int kc = 0; kc < 4; ++kc) {
            short8 b = *(const short8*)(wrow + kc * 32);
            acc[nt] = __builtin_amdgcn_mfma_f32_16x16x32_bf16(a[kc], b, acc[nt], 0, 0, 0);
        }
    }

    int mrow0 = blockIdx.x * 64 + wave * 16 + quad * 4;
#pragma unroll
    for (int nt = 0; nt < 8; ++nt) {
        int n = nt * 16 + l16;
        float bn = bias[n];
#pragma unroll
        for (int r = 0; r < 4; ++r) {
            int mm = mrow0 + r;
            if (mm < N_NODES) {
                float h = fmaxf(acc[nt][r] + bn, 0.f);
                Hb[(size_t)mm * 128 + n] = f2b_rne(h);
            }
        }
    }
}

// ---- fused final pool (layer 3) + 3-stage classifier, one block per graph --
__global__ __launch_bounds__(128) void k_cls(const unsigned short* __restrict__ Hb,
                                             const int* __restrict__ startv,
                                             const int* __restrict__ endv,
                                             const float* __restrict__ gr,
                                             const float* __restrict__ cw1,
                                             const float* __restrict__ cb1,
                                             const float* __restrict__ cw2,
                                             const float* __restrict__ cb2,
                                             const float* __restrict__ cw3,
                                             const float* __restrict__ cb3,
                                             float* __restrict__ out) {
    __shared__ float row[512];
    __shared__ float h1[128];
    __shared__ float h2[64];
    int g = blockIdx.x, tid = threadIdx.x;
    for (int i = tid; i < 384; i += 128) row[i] = gr[(size_t)g * 512 + i];
    {   // pool layer-3 column tid (same loop shape as the original k_pool-128)
        int s = startv[g], e = endv[g];
        float acc = 0.f;
        int r = s;
        for (; r + 4 <= e; r += 4) {
            unsigned short a0 = Hb[(size_t)r * 128 + tid];
            unsigned short a1 = Hb[(size_t)(r + 1) * 128 + tid];
            unsigned short a2 = Hb[(size_t)(r + 2) * 128 + tid];
            unsigned short a3 = Hb[(size_t)(r + 3) * 128 + tid];
            acc += bits2f(a0) + bits2f(a1) + bits2f(a2) + bits2f(a3);
        }
        for (; r < e; ++r) acc += bits2f(Hb[(size_t)r * 128 + tid]);
        row[384 + tid] = acc;
    }
    __syncthreads();
    float a1 = cb1[tid];
    for (int k = 0; k < 512; ++k) a1 = fmaf(row[k], cw1[k * 128 + tid], a1);
    h1[tid] = fmaxf(a1, 0.f);
    __syncthreads();
    if (tid < 64) {
        float a2 = cb2[tid];
        for (int k = 0; k < 128; ++k) a2 = fmaf(h1[k], cw2[k * 64 + tid], a2);
        h2[tid] = fmaxf(a2, 0.f);
    }
    __syncthreads();
    if (tid < 2) {
        float a3 = cb3[tid];
        for (int k = 0; k < 64; ++k) a3 = fmaf(h2[k], cw3[k * 2 + tid], a3);
        out[(size_t)g * 2 + tid] = a3;
    }
}

// ---------------- launch ----------------

extern "C" void kernel_launch(void* const* d_in, const int* in_sizes, int n_in,
                              void* d_out, int out_size, void* d_ws, size_t ws_size,
                              hipStream_t stream) {
    const float* x = (const float*)d_in[0];
    const int* ei = (const int*)d_in[1];
    const int* batch = (const int*)d_in[2];
    const float* b1 = (const float*)d_in[4];
    const float* g1 = (const float*)d_in[5];
    const float* be1 = (const float*)d_in[6];
    const float* b2 = (const float*)d_in[8];
    const float* lb1 = (const float*)d_in[10];
    const float* lg1 = (const float*)d_in[11];
    const float* lbe1 = (const float*)d_in[12];
    const float* lb2 = (const float*)d_in[14];
    const float* cw1 = (const float*)d_in[15];
    const float* cb1 = (const float*)d_in[16];
    const float* cw2 = (const float*)d_in[17];
    const float* cb2 = (const float*)d_in[18];
    const float* cw3 = (const float*)d_in[19];
    const float* cb3 = (const float*)d_in[20];

    // workspace layout (float units; every segment 16B-aligned)
    float* ws = (float*)d_ws;
    unsigned short* Yb = (unsigned short*)ws;                     // N_PAD*128 bf16
    float* gr = ws + (size_t)N_PAD * 64;                          // 1024*512
    float* gr1 = gr + (size_t)N_GRAPHS * 512;                     // 1024*128 (unused)
    float* gr2 = gr1 + (size_t)N_GRAPHS * 128;                    // 1024*64  (unused)
    float* stats = gr2 + (size_t)N_GRAPHS * 64;                   // 256
    float* partials = stats + 256;                                // 1563*256
    float* pred = partials + (size_t)MM_BLOCKS * 256;             // 64*256
    float* p_end = pred + (size_t)RED_BLOCKS * 256;
    int* startv = (int*)p_end;
    int* endv = startv + N_GRAPHS;
    unsigned short* Wt = (unsigned short*)(endv + N_GRAPHS);      // 8*16384 bf16
    unsigned short* A = Wt + (size_t)8 * 16384;                   // N_PAD*128 bf16
    unsigned short* Hb0 = A + (size_t)N_PAD * 128;                // bf16(x)
    unsigned short* Hb1 = Hb0 + (size_t)N_NODES * 128;            // layer H
    int* degC = (int*)(Hb1 + (size_t)N_NODES * 128);              // NCHUNK*N_NODES
    int* deg = degC + (size_t)NCHUNK * N_NODES;                   // N_NODES
    int* rank = deg + N_NODES;                                    // N_EDGES
    int* offarr = rank + N_EDGES;                                 // N_NODES+1
    int* csr_src = offarr + (N_NODES + 4);                        // N_EDGES
    int* bsum = csr_src + N_EDGES;                                // 256
    int* bbase = bsum + 256;                                      // 256
    int* ctr = bbase + 256;                                       // 2 (redfin, scanAB)

    k_cvt0<<<12500, 256, 0, stream>>>((const float4*)x, (ushort4*)Hb0, startv, endv, ctr);
    k_deg2b<<<NCHUNK * NRANGES + 391, 256, 0, stream>>>(ei, degC, rank, batch, startv, endv);
    k_comb<<<(N_NODES + 255) / 256, 256, 0, stream>>>(degC, deg);
    k_scanAB<<<256, 256, 0, stream>>>(deg, bsum, bbase, &offarr[N_NODES], ctr + 1);
    k_scanC<<<256, 256, 0, stream>>>(deg, bbase, offarr);
    k_filltw<<<N_EDGES / 256 + 512, 256, 0, stream>>>(ei, offarr, degC, rank, csr_src,
                                                      (const float*)d_in[3], (const float*)d_in[7],
                                                      (const float*)d_in[9], (const float*)d_in[13], Wt);

    for (int l = 0; l < 4; ++l) {
        const unsigned short* aggIn = (l == 0) ? Hb0 : Hb1;

        const unsigned short* W1t = Wt + (size_t)((l == 0) ? 0 : (1 + l)) * 16384;
        const unsigned short* W2t = Wt + (size_t)((l == 0) ? 1 : (4 + l)) * 16384;
        const float* B1 = (l == 0) ? b1 : lb1 + (size_t)(l - 1) * 128;
        const float* B2 = (l == 0) ? b2 : lb2 + (size_t)(l - 1) * 128;
        const float* G = (l == 0) ? g1 : lg1 + (size_t)(l - 1) * 128;
        const float* BE = (l == 0) ? be1 : lbe1 + (size_t)(l - 1) * 128;

        // l==0: pure agg. l>=1: + 1024 pool blocks for the previous layer's H
        // (both roles only READ Hb1; mm2 overwrites it afterwards).
        int grid = AGG_BLOCKS + ((l > 0) ? N_GRAPHS : 0);
        k_aggpool<<<grid, 256, 0, stream>>>((const uint4*)aggIn, offarr, csr_src,
                                            (uint4*)A, Hb1, startv, endv, gr,
                                            (l > 0) ? (l - 1) * DIM : 0);
        k_mm1<<<MM_BLOCKS, 256, 0, stream>>>(A, W1t, B1, Yb, partials);
        k_redfin<<<RED_BLOCKS, 256, 0, stream>>>(partials, pred, stats, G, BE, ctr);
        k_mm2<<<MM_BLOCKS, 256, 0, stream>>>(Yb, W2t, B2, stats, Hb1);
    }

    // final pool (layer 3) fused into the classifier
    k_cls<<<N_GRAPHS, 128, 0, stream>>>(Hb1, startv, endv, gr,
                                        cw1, cb1, cw2, cb2, cw3, cb3, (float*)d_out);
}